// Round 10
// baseline (155.335 us; speedup 1.0000x reference)
//
#include <hip/hip_runtime.h>
#include <math.h>

#ifndef M_PI
#define M_PI 3.14159265358979323846
#endif

#define BATCHES 256
#define S_LEN   131072

// One kernel, fully independent blocks (truncated-warmup linear recurrence).
// Block = 256 threads x 64-sample chunks = 16384-sample segment.
// Warmup: 16 extra chunks (1024 samples); worst pole radius 0.9894 ->
// forgotten-state error ~2e-4 (threshold 2e-2). Verified absmax 0.0039 (r7-r9).
//
// r10: phase 3 via homogeneous correction -- phase 1 keeps the band-sum
// zero-state output in 64 VGPRs (float4 szs[16]); phase 2 stores H_k(t) to
// LDS; phase 3 = szs + c1*H(t) + c2*H(t-1), NO x re-read, NO serial chain.
// Occupancy pinned at 4 blocks/CU (launch_bounds(256,4)): r8/r9 proved any
// min-waves>4 causes a VGPR cliff (40/32 regs, spills) + L3 thrash.
#define TPB   256
#define CCH   64
#define SEGS  8                      // segments per row
#define SEG_SAMPS (TPB * CCH)        // 16384
#define WCH   16                     // warmup chunks
#define PSTR  288                    // padded per-band state stride (chunks)
#define OBSTR 33                     // half staging stride (32 samples + pad)
#define HOFF  (TPB * OBSTR)          // 8448: float offset of H sequences
#define HSTR  68                     // per-band H stride (64 + pad, 16B aligned)
#define LDSF  (HOFF + 3 * HSTR)      // 8652 floats = 34608 B -> 4 blocks/CU

__device__ __forceinline__ void compute_coeffs(float level_in, float b0[3], float na1[3], float na2[3]) {
    const float FD[3] = {270.0f, 800.0f, 2300.0f};
    const float FN[3] = {500.0f, 1500.0f, 2500.0f};
    const float FB[3] = {730.0f, 2100.0f, 3000.0f};
    float level = fminf(fmaxf(level_in, 0.0f), 1.0f);
    float t_low  = fminf(fmaxf(level * 2.0f, 0.0f), 1.0f);
    float t_high = fminf(fmaxf((level - 0.5f) * 2.0f, 0.0f), 1.0f);
    bool hi = (level >= 0.5f);
    const float W0 = (float)(2.0 * M_PI / 16000.0);
    #pragma unroll
    for (int k = 0; k < 3; ++k) {
        float f, q;
        if (hi) { f = (1.0f - t_high) * FN[k] + t_high * FB[k];
                  q = (1.0f - t_high) * 8.0f  + t_high * 12.0f; }
        else    { f = (1.0f - t_low) * FD[k] + t_low * FN[k];
                  q = (1.0f - t_low) * 5.0f  + t_low * 8.0f; }
        float omega = W0 * f;
        float sn = sinf(omega), cs = cosf(omega);
        float alpha = sn / (2.0f * fmaxf(q, 0.5f));
        float a0 = 1.0f + alpha;
        b0[k]  = alpha / a0;             // b2 == -b0 exactly
        na1[k] = (2.0f * cs) / a0;       // -a1
        na2[k] = -((1.0f - alpha) / a0); // -a2
    }
}

#define STEP3(XT, XTM2, SUMV)                                                    \
    {                                                                            \
        float d = (XT) - (XTM2);                                                 \
        float e0 = fmaf(b0[0], d, na2[0] * y2[0]);                               \
        float e1 = fmaf(b0[1], d, na2[1] * y2[1]);                               \
        float e2 = fmaf(b0[2], d, na2[2] * y2[2]);                               \
        float yy0 = fmaf(na1[0], y1[0], e0);                                     \
        float yy1 = fmaf(na1[1], y1[1], e1);                                     \
        float yy2 = fmaf(na1[2], y1[2], e2);                                     \
        y2[0] = y1[0]; y1[0] = yy0;                                              \
        y2[1] = y1[1]; y1[1] = yy1;                                              \
        y2[2] = y1[2]; y1[2] = yy2;                                              \
        SUMV = (yy0 + yy1 + yy2);                                                \
    }

// 2x2 matrix multiply: R = X * Y
#define MMUL(R00,R01,R10,R11, X00,X01,X10,X11, Y00,Y01,Y10,Y11)                  \
    {                                                                            \
        R00 = X00*Y00 + X01*Y10; R01 = X00*Y01 + X01*Y11;                        \
        R10 = X10*Y00 + X11*Y10; R11 = X10*Y01 + X11*Y11;                        \
    }

__global__ __launch_bounds__(TPB, 4)
void formant_onepass(const float* __restrict__ x, const float* __restrict__ lvl,
                     float* __restrict__ out)
{
    __shared__ float lds[LDSF];   // staging 0..8447 (scan region aliases 0..1727), H at 8448+

    const int tid = threadIdx.x;
    const int row = blockIdx.x >> 3;
    const int seg = blockIdx.x & (SEGS - 1);

    float b0[3], na1[3], na2[3];
    compute_coeffs(lvl[row], b0, na1, na2);

    const float* xrow = x + (size_t)row * S_LEN;
    const size_t segBase = (size_t)seg * SEG_SAMPS;
    const float* xc = xrow + segBase + (size_t)tid * CCH;

    float xm1_0 = 0.f, xm2_0 = 0.f;
    if (seg > 0 || tid > 0) { float2 t2 = *(const float2*)(xc - 2); xm2_0 = t2.x; xm1_0 = t2.y; }

    // -------- phase 1a: main-chunk zero-state; band-sum output held in regs --------
    float4 szs[16];   // 64 VGPR: zero-state band-sum per sample
    {
        float y1[3] = {0.f,0.f,0.f}, y2[3] = {0.f,0.f,0.f};
        float p1 = xm1_0, p2 = xm2_0;
        const float4* xv = (const float4*)xc;
        float4 buf[4];
        #pragma unroll
        for (int j = 0; j < 4; ++j) buf[j] = xv[j];
        #pragma unroll
        for (int i = 0; i < 16; ++i) {
            float4 q = buf[i & 3];
            if (i + 4 < 16) buf[i & 3] = xv[i + 4];
            STEP3(q.x, p2, szs[i].x)
            STEP3(q.y, p1, szs[i].y)
            STEP3(q.z, q.x, szs[i].z)
            STEP3(q.w, q.y, szs[i].w)
            p2 = q.z; p1 = q.w;
        }
        lds[0*PSTR + WCH + tid] = y1[0]; lds[1*PSTR + WCH + tid] = y2[0];
        lds[2*PSTR + WCH + tid] = y1[1]; lds[3*PSTR + WCH + tid] = y2[1];
        lds[4*PSTR + WCH + tid] = y1[2]; lds[5*PSTR + WCH + tid] = y2[2];
    }

    // -------- phase 1b: warmup chunks (threads 0..15) --------
    if (tid < WCH) {
        if (seg == 0) {
            #pragma unroll
            for (int e = 0; e < 6; ++e) lds[e*PSTR + tid] = 0.f;   // exact: true zero state
        } else {
            const float* xw = xrow + segBase - (size_t)(WCH * CCH) + (size_t)tid * CCH;
            float2 t2 = *(const float2*)(xw - 2);
            float y1[3] = {0.f,0.f,0.f}, y2[3] = {0.f,0.f,0.f};
            float p2 = t2.x, p1 = t2.y, dummy;
            const float4* xv = (const float4*)xw;
            float4 buf[4];
            #pragma unroll
            for (int j = 0; j < 4; ++j) buf[j] = xv[j];
            #pragma unroll
            for (int i = 0; i < 16; ++i) {
                float4 q = buf[i & 3];
                if (i + 4 < 16) buf[i & 3] = xv[i + 4];
                STEP3(q.x, p2, dummy)
                STEP3(q.y, p1, dummy)
                STEP3(q.z, q.x, dummy)
                STEP3(q.w, q.y, dummy)
                p2 = q.z; p1 = q.w;
            }
            (void)dummy;
            lds[0*PSTR + tid] = y1[0]; lds[1*PSTR + tid] = y2[0];
            lds[2*PSTR + tid] = y1[1]; lds[3*PSTR + tid] = y2[1];
            lds[4*PSTR + tid] = y1[2]; lds[5*PSTR + tid] = y2[2];
        }
    }
    __syncthreads();

    // -------- phase 2: block-local affine scan + store H_k(t) sequences --------
    // lanes 0..15 fold 5 chunks, lanes 16..63 fold 4 (16*5 + 48*4 = 272)
    {
        const int wv = tid >> 6, ln = tid & 63;
        if (wv < 3) {
            const float A1 = na1[wv], A2 = na2[wv];
            float hm1 = 1.f, hm2 = 0.f, hm3 = 0.f;   // hm1 = H(-1) = 1
            for (int i = 0; i < CCH; ++i) {
                float h = fmaf(A1, hm1, A2 * hm2);
                hm3 = hm2; hm2 = hm1; hm1 = h;
                if (ln == 0) lds[HOFF + wv * HSTR + i] = h;   // H(i)
            }
            const float H00 = hm1, H01 = A2 * hm2;
            const float H10 = hm2, H11 = A2 * hm3;

            float* z1p = lds + (2*wv) * PSTR;
            float* z2p = lds + (2*wv + 1) * PSTR;

            const int cnt = (ln < 16) ? 5 : 4;
            const int beg = (ln < 16) ? 5 * ln : 80 + 4 * (ln - 16);

            float s1 = 0.f, s2 = 0.f;
            for (int j = 0; j < cnt; ++j) {
                float z1 = z1p[beg + j], z2 = z2p[beg + j];
                float n1 = z1 + H00 * s1 + H01 * s2;
                float n2 = z2 + H10 * s1 + H11 * s2;
                s1 = n1; s2 = n2;
            }
            float B00,B01,B10,B11, C00,C01,C10,C11;
            MMUL(B00,B01,B10,B11, H00,H01,H10,H11, H00,H01,H10,H11)   // H^2
            MMUL(C00,C01,C10,C11, B00,B01,B10,B11, B00,B01,B10,B11)   // H^4
            float A00 = C00, A01 = C01, A10 = C10, A11 = C11;
            if (cnt == 5) {
                float D00,D01,D10,D11;
                MMUL(D00,D01,D10,D11, C00,C01,C10,C11, H00,H01,H10,H11)
                A00 = D00; A01 = D01; A10 = D10; A11 = D11;
            }
            float bb1 = s1, bb2 = s2;
            for (int d = 1; d < 64; d <<= 1) {
                float iA00 = __shfl_up(A00, d), iA01 = __shfl_up(A01, d);
                float iA10 = __shfl_up(A10, d), iA11 = __shfl_up(A11, d);
                float ib1  = __shfl_up(bb1, d), ib2  = __shfl_up(bb2, d);
                if (ln >= d) {
                    float nb1 = A00 * ib1 + A01 * ib2 + bb1;
                    float nb2 = A10 * ib1 + A11 * ib2 + bb2;
                    float n00, n01, n10, n11;
                    MMUL(n00,n01,n10,n11, A00,A01,A10,A11, iA00,iA01,iA10,iA11)
                    A00 = n00; A01 = n01; A10 = n10; A11 = n11;
                    bb1 = nb1; bb2 = nb2;
                }
            }
            float e1 = __shfl_up(bb1, 1), e2 = __shfl_up(bb2, 1);
            if (ln == 0) { e1 = 0.f; e2 = 0.f; }

            // replay: overwrite z with corrected chunk-ENTRY states
            s1 = e1; s2 = e2;
            for (int j = 0; j < cnt; ++j) {
                int w = beg + j;
                float z1 = z1p[w], z2 = z2p[w];
                z1p[w] = s1; z2p[w] = s2;
                float n1 = z1 + H00 * s1 + H01 * s2;
                float n2 = z2 + H10 * s1 + H11 * s2;
                s1 = n1; s2 = n2;
            }
        }
    }
    __syncthreads();

    // -------- phase 3: out = is3*(szs + c1*H(t) + c2*H(t-1)); pure write, no chain --------
    float c1[3], c2[3];
    #pragma unroll
    for (int k = 0; k < 3; ++k) {
        c1[k] = lds[(2*k) * PSTR + WCH + tid];              // s1 (entry y[-1])
        c2[k] = na2[k] * lds[(2*k + 1) * PSTR + WCH + tid]; // na2 * s2 (entry y[-2])
    }
    __syncthreads();   // scan region now reusable as staging

    {
        const float is3 = 0.57735026918962576f;   // 1/sqrt(3)
        float* myob = lds + tid * OBSTR;
        float4* obase = (float4*)(out + (size_t)row * S_LEN + segBase);
        float hprev[3] = {1.f, 1.f, 1.f};         // H(-1) = 1

        #pragma unroll
        for (int h2 = 0; h2 < 2; ++h2) {          // two 32-sample halves
            #pragma unroll
            for (int i8 = 0; i8 < 8; ++i8) {
                const int i = h2 * 8 + i8;
                const int t = i * 4;
                float4 s = szs[i];
                float ox = s.x, oy = s.y, oz = s.z, ow = s.w;
                #pragma unroll
                for (int k = 0; k < 3; ++k) {
                    float4 hv = *(const float4*)&lds[HOFF + k * HSTR + t];  // H(t..t+3), broadcast
                    ox = fmaf(c1[k], hv.x, fmaf(c2[k], hprev[k], ox));
                    oy = fmaf(c1[k], hv.y, fmaf(c2[k], hv.x,     oy));
                    oz = fmaf(c1[k], hv.z, fmaf(c2[k], hv.y,     oz));
                    ow = fmaf(c1[k], hv.w, fmaf(c2[k], hv.z,     ow));
                    hprev[k] = hv.w;
                }
                // scalar LDS writes: bank=(33*tid + 4*i8+k)%32 -> exactly 2-way (free)
                myob[4*i8 + 0] = ox * is3;
                myob[4*i8 + 1] = oy * is3;
                myob[4*i8 + 2] = oz * is3;
                myob[4*i8 + 3] = ow * is3;
            }
            __syncthreads();
            // cooperative store: 2048 float4 (32 KB), full 64B lines
            #pragma unroll
            for (int j = 0; j < 8; ++j) {
                int f   = j * TPB + tid;
                int ch  = f >> 3;                 // local chunk
                int off = f & 7;                  // float4 within half
                const float* p = lds + ch * OBSTR + off * 4;
                float4 o = { p[0], p[1], p[2], p[3] };
                obase[(size_t)ch * (CCH / 4) + h2 * 8 + off] = o;
            }
            __syncthreads();
        }
    }
}

extern "C" void kernel_launch(void* const* d_in, const int* in_sizes, int n_in,
                              void* d_out, int out_size, void* d_ws, size_t ws_size,
                              hipStream_t stream) {
    const float* audio = (const float*)d_in[0];
    const float* level = (const float*)d_in[1];
    float* out = (float*)d_out;
    (void)in_sizes; (void)n_in; (void)d_ws; (void)ws_size; (void)out_size;

    formant_onepass<<<BATCHES * SEGS, TPB, 0, stream>>>(audio, level, out);
}

// Round 11
// 82.470 us; speedup vs baseline: 1.8835x; 1.8835x over previous
//
#include <hip/hip_runtime.h>
#include <math.h>

#ifndef M_PI
#define M_PI 3.14159265358979323846
#endif

#define BATCHES 256
#define S_LEN   131072

// One kernel, fully independent blocks (truncated-warmup linear recurrence).
// Block = 256 threads x 64-sample chunks = 16384-sample segment.
// Warmup: 16 extra chunks (1024 samples); worst pole radius 0.9894 ->
// forgotten-state error ~2e-4 (threshold 2e-2). Verified absmax 0.0039 (r7-r10).
//
// Operating point (hard-won): 4 blocks/CU, launch_bounds(256,4), LDS 33.8KB,
// OBSTR=33 halves staging, NO cross-phase register arrays. Evidence:
//  - r8 (256,8): VGPR 32, FETCH 237MB, 100us.  r9 (256,6): VGPR 40, 204MB, 91us.
//  - r10 szs[16] in regs: compiler clamps to 64 VGPR -> full spill, 155us.
// r11 change vs r7: rolling x prefetch depth 4 -> 8 in all streaming loops
// (depth 4 = ~300-600cyc slack vs ~900cyc HBM latency; depth 8 covers it).
#define TPB   256
#define CCH   64
#define SEGS  8                      // segments per row
#define SEG_SAMPS (TPB * CCH)        // 16384
#define WCH   16                     // warmup chunks
#define PSTR  288                    // padded per-band state stride (chunks)
#define OBSTR 33                     // half staging stride (32 samples + pad)
                                     // LDS = 256*33*4 = 33792 B -> 4 blocks/CU

__device__ __forceinline__ void compute_coeffs(float level_in, float b0[3], float na1[3], float na2[3]) {
    const float FD[3] = {270.0f, 800.0f, 2300.0f};
    const float FN[3] = {500.0f, 1500.0f, 2500.0f};
    const float FB[3] = {730.0f, 2100.0f, 3000.0f};
    float level = fminf(fmaxf(level_in, 0.0f), 1.0f);
    float t_low  = fminf(fmaxf(level * 2.0f, 0.0f), 1.0f);
    float t_high = fminf(fmaxf((level - 0.5f) * 2.0f, 0.0f), 1.0f);
    bool hi = (level >= 0.5f);
    const float W0 = (float)(2.0 * M_PI / 16000.0);
    #pragma unroll
    for (int k = 0; k < 3; ++k) {
        float f, q;
        if (hi) { f = (1.0f - t_high) * FN[k] + t_high * FB[k];
                  q = (1.0f - t_high) * 8.0f  + t_high * 12.0f; }
        else    { f = (1.0f - t_low) * FD[k] + t_low * FN[k];
                  q = (1.0f - t_low) * 5.0f  + t_low * 8.0f; }
        float omega = W0 * f;
        float sn = sinf(omega), cs = cosf(omega);
        float alpha = sn / (2.0f * fmaxf(q, 0.5f));
        float a0 = 1.0f + alpha;
        b0[k]  = alpha / a0;             // b2 == -b0 exactly
        na1[k] = (2.0f * cs) / a0;       // -a1
        na2[k] = -((1.0f - alpha) / a0); // -a2
    }
}

#define STEP3(XT, XTM2, SUMV)                                                    \
    {                                                                            \
        float d = (XT) - (XTM2);                                                 \
        float e0 = fmaf(b0[0], d, na2[0] * y2[0]);                               \
        float e1 = fmaf(b0[1], d, na2[1] * y2[1]);                               \
        float e2 = fmaf(b0[2], d, na2[2] * y2[2]);                               \
        float yy0 = fmaf(na1[0], y1[0], e0);                                     \
        float yy1 = fmaf(na1[1], y1[1], e1);                                     \
        float yy2 = fmaf(na1[2], y1[2], e2);                                     \
        y2[0] = y1[0]; y1[0] = yy0;                                              \
        y2[1] = y1[1]; y1[1] = yy1;                                              \
        y2[2] = y1[2]; y1[2] = yy2;                                              \
        SUMV = (yy0 + yy1 + yy2);                                                \
    }

// 2x2 matrix multiply: R = X * Y
#define MMUL(R00,R01,R10,R11, X00,X01,X10,X11, Y00,Y01,Y10,Y11)                  \
    {                                                                            \
        R00 = X00*Y00 + X01*Y10; R01 = X00*Y01 + X01*Y11;                        \
        R10 = X10*Y00 + X11*Y10; R11 = X10*Y01 + X11*Y11;                        \
    }

__global__ __launch_bounds__(TPB, 4)
void formant_onepass(const float* __restrict__ x, const float* __restrict__ lvl,
                     float* __restrict__ out)
{
    __shared__ float lds[TPB * OBSTR];   // 33792 B; scan uses first 6*288=1728 floats

    const int tid = threadIdx.x;
    const int row = blockIdx.x >> 3;
    const int seg = blockIdx.x & (SEGS - 1);

    float b0[3], na1[3], na2[3];
    compute_coeffs(lvl[row], b0, na1, na2);

    const float* xrow = x + (size_t)row * S_LEN;
    const size_t segBase = (size_t)seg * SEG_SAMPS;
    const float* xc = xrow + segBase + (size_t)tid * CCH;

    float xm1_0 = 0.f, xm2_0 = 0.f;
    if (seg > 0 || tid > 0) { float2 t2 = *(const float2*)(xc - 2); xm2_0 = t2.x; xm1_0 = t2.y; }

    // -------- phase 1a: main-chunk zero-state (8-deep rolling prefetch) --------
    {
        float y1[3] = {0.f,0.f,0.f}, y2[3] = {0.f,0.f,0.f};
        float p1 = xm1_0, p2 = xm2_0, dummy;
        const float4* xv = (const float4*)xc;
        float4 buf[8];
        #pragma unroll
        for (int j = 0; j < 8; ++j) buf[j] = xv[j];
        #pragma unroll
        for (int i = 0; i < 16; ++i) {
            float4 q = buf[i & 7];
            if (i + 8 < 16) buf[i & 7] = xv[i + 8];
            STEP3(q.x, p2, dummy)
            STEP3(q.y, p1, dummy)
            STEP3(q.z, q.x, dummy)
            STEP3(q.w, q.y, dummy)
            p2 = q.z; p1 = q.w;
        }
        (void)dummy;
        lds[0*PSTR + WCH + tid] = y1[0]; lds[1*PSTR + WCH + tid] = y2[0];
        lds[2*PSTR + WCH + tid] = y1[1]; lds[3*PSTR + WCH + tid] = y2[1];
        lds[4*PSTR + WCH + tid] = y1[2]; lds[5*PSTR + WCH + tid] = y2[2];
    }

    // -------- phase 1b: warmup chunks (threads 0..15) --------
    if (tid < WCH) {
        if (seg == 0) {
            #pragma unroll
            for (int e = 0; e < 6; ++e) lds[e*PSTR + tid] = 0.f;   // exact: true zero state
        } else {
            const float* xw = xrow + segBase - (size_t)(WCH * CCH) + (size_t)tid * CCH;
            float2 t2 = *(const float2*)(xw - 2);
            float y1[3] = {0.f,0.f,0.f}, y2[3] = {0.f,0.f,0.f};
            float p2 = t2.x, p1 = t2.y, dummy;
            const float4* xv = (const float4*)xw;
            float4 buf[8];
            #pragma unroll
            for (int j = 0; j < 8; ++j) buf[j] = xv[j];
            #pragma unroll
            for (int i = 0; i < 16; ++i) {
                float4 q = buf[i & 7];
                if (i + 8 < 16) buf[i & 7] = xv[i + 8];
                STEP3(q.x, p2, dummy)
                STEP3(q.y, p1, dummy)
                STEP3(q.z, q.x, dummy)
                STEP3(q.w, q.y, dummy)
                p2 = q.z; p1 = q.w;
            }
            (void)dummy;
            lds[0*PSTR + tid] = y1[0]; lds[1*PSTR + tid] = y2[0];
            lds[2*PSTR + tid] = y1[1]; lds[3*PSTR + tid] = y2[1];
            lds[4*PSTR + tid] = y1[2]; lds[5*PSTR + tid] = y2[2];
        }
    }
    __syncthreads();

    // -------- phase 2: block-local affine scan over 272 chunk states --------
    // lanes 0..15 fold 5 chunks, lanes 16..63 fold 4 (16*5 + 48*4 = 272)
    {
        const int wv = tid >> 6, ln = tid & 63;
        if (wv < 3) {
            const float A1 = na1[wv], A2 = na2[wv];
            float hm1 = 1.f, hm2 = 0.f, hm3 = 0.f;
            for (int i = 0; i < CCH; ++i) {
                float h = fmaf(A1, hm1, A2 * hm2);
                hm3 = hm2; hm2 = hm1; hm1 = h;
            }
            const float H00 = hm1, H01 = A2 * hm2;
            const float H10 = hm2, H11 = A2 * hm3;

            float* z1p = lds + (2*wv) * PSTR;
            float* z2p = lds + (2*wv + 1) * PSTR;

            const int cnt = (ln < 16) ? 5 : 4;
            const int beg = (ln < 16) ? 5 * ln : 80 + 4 * (ln - 16);

            float s1 = 0.f, s2 = 0.f;
            for (int j = 0; j < cnt; ++j) {
                float z1 = z1p[beg + j], z2 = z2p[beg + j];
                float n1 = z1 + H00 * s1 + H01 * s2;
                float n2 = z2 + H10 * s1 + H11 * s2;
                s1 = n1; s2 = n2;
            }
            float B00,B01,B10,B11, C00,C01,C10,C11;
            MMUL(B00,B01,B10,B11, H00,H01,H10,H11, H00,H01,H10,H11)   // H^2
            MMUL(C00,C01,C10,C11, B00,B01,B10,B11, B00,B01,B10,B11)   // H^4
            float A00 = C00, A01 = C01, A10 = C10, A11 = C11;
            if (cnt == 5) {
                float D00,D01,D10,D11;
                MMUL(D00,D01,D10,D11, C00,C01,C10,C11, H00,H01,H10,H11)
                A00 = D00; A01 = D01; A10 = D10; A11 = D11;
            }
            float bb1 = s1, bb2 = s2;
            for (int d = 1; d < 64; d <<= 1) {
                float iA00 = __shfl_up(A00, d), iA01 = __shfl_up(A01, d);
                float iA10 = __shfl_up(A10, d), iA11 = __shfl_up(A11, d);
                float ib1  = __shfl_up(bb1, d), ib2  = __shfl_up(bb2, d);
                if (ln >= d) {
                    float nb1 = A00 * ib1 + A01 * ib2 + bb1;
                    float nb2 = A10 * ib1 + A11 * ib2 + bb2;
                    float n00, n01, n10, n11;
                    MMUL(n00,n01,n10,n11, A00,A01,A10,A11, iA00,iA01,iA10,iA11)
                    A00 = n00; A01 = n01; A10 = n10; A11 = n11;
                    bb1 = nb1; bb2 = nb2;
                }
            }
            float e1 = __shfl_up(bb1, 1), e2 = __shfl_up(bb2, 1);
            if (ln == 0) { e1 = 0.f; e2 = 0.f; }

            // replay: overwrite z with corrected chunk-ENTRY states
            s1 = e1; s2 = e2;
            for (int j = 0; j < cnt; ++j) {
                int w = beg + j;
                float z1 = z1p[w], z2 = z2p[w];
                z1p[w] = s1; z2p[w] = s2;
                float n1 = z1 + H00 * s1 + H01 * s2;
                float n2 = z2 + H10 * s1 + H11 * s2;
                s1 = n1; s2 = n2;
            }
        }
    }
    __syncthreads();

    // -------- phase 3: recurrence with corrected entry; x re-read (L2/L3-hot);
    //          half-staged coalesced output, 8-deep rolling prefetch --------
    float y1[3], y2[3];
    y1[0] = lds[0*PSTR + WCH + tid]; y2[0] = lds[1*PSTR + WCH + tid];
    y1[1] = lds[2*PSTR + WCH + tid]; y2[1] = lds[3*PSTR + WCH + tid];
    y1[2] = lds[4*PSTR + WCH + tid]; y2[2] = lds[5*PSTR + WCH + tid];
    __syncthreads();   // scan region now reusable as staging

    {
        float p1 = xm1_0, p2 = xm2_0;
        const float is3 = 0.57735026918962576f;   // 1/sqrt(3)
        const float4* xv = (const float4*)xc;
        float* myob = lds + tid * OBSTR;
        float4* obase = (float4*)(out + (size_t)row * S_LEN + segBase);

        float4 buf[8];
        #pragma unroll
        for (int j = 0; j < 8; ++j) buf[j] = xv[j];

        #pragma unroll
        for (int h2 = 0; h2 < 2; ++h2) {          // two 32-sample halves
            #pragma unroll
            for (int i8 = 0; i8 < 8; ++i8) {
                const int i = h2 * 8 + i8;
                float4 q = buf[i & 7];
                if (i + 8 < 16) buf[i & 7] = xv[i + 8];
                float4 o;
                STEP3(q.x, p2, o.x)
                STEP3(q.y, p1, o.y)
                STEP3(q.z, q.x, o.z)
                STEP3(q.w, q.y, o.w)
                p2 = q.z; p1 = q.w;
                // scalar LDS writes: bank=(33*tid + 4*i8+k)%32 -> exactly 2-way (free)
                myob[4*i8 + 0] = o.x * is3;
                myob[4*i8 + 1] = o.y * is3;
                myob[4*i8 + 2] = o.z * is3;
                myob[4*i8 + 3] = o.w * is3;
            }
            __syncthreads();
            // cooperative store: 2048 float4 (32 KB), full 64B lines
            #pragma unroll
            for (int j = 0; j < 8; ++j) {
                int f   = j * TPB + tid;
                int ch  = f >> 3;                 // local chunk
                int off = f & 7;                  // float4 within half
                const float* p = lds + ch * OBSTR + off * 4;
                float4 o = { p[0], p[1], p[2], p[3] };
                obase[(size_t)ch * (CCH / 4) + h2 * 8 + off] = o;
            }
            __syncthreads();
        }
    }
}

extern "C" void kernel_launch(void* const* d_in, const int* in_sizes, int n_in,
                              void* d_out, int out_size, void* d_ws, size_t ws_size,
                              hipStream_t stream) {
    const float* audio = (const float*)d_in[0];
    const float* level = (const float*)d_in[1];
    float* out = (float*)d_out;
    (void)in_sizes; (void)n_in; (void)d_ws; (void)ws_size; (void)out_size;

    formant_onepass<<<BATCHES * SEGS, TPB, 0, stream>>>(audio, level, out);
}

// Round 12
// 58.913 us; speedup vs baseline: 2.6367x; 1.3999x over previous
//
#include <hip/hip_runtime.h>
#include <math.h>

#ifndef M_PI
#define M_PI 3.14159265358979323846
#endif

#define BATCHES 256
#define S_LEN   131072

// One kernel, independent blocks, truncated-warmup linear recurrence.
// Block = 256 threads x 32-sample chunks = 8192-sample segment; warmup 24
// chunks (768 samples): worst pole r=0.98948 -> r^768 ~ 3e-4, error ~2.8e-3
// vs threshold 2.03e-2. Phase 3 uses the homogeneous-correction identity
// (validated numerically in r10): y(t) = y_zs(t) + c1*H(t) + c2*H(t-1),
// with y_zs band-sum staged in LDS (fits at CCH=32) and H in LDS -- no x
// re-read, no serial chain, direct coalesced global stores, 2 barriers.
//
// Operating point (r7-r11 evidence): 4 blocks/CU pinned by LDS ~40KB,
// launch_bounds(256,4), no cross-phase register arrays (compiler clamps to
// <=64 VGPR and spills anything bigger: r8=32, r9=40, r10=64+spill).
#define TPB   256
#define CCH   32
#define SEGS  16                      // segments per row
#define SEG_SAMPS (TPB * CCH)         // 8192
#define WCH   24                      // warmup chunks
#define NCH   (TPB + WCH)             // 280 chunks scanned
#define OBSTR 33                      // staging stride (32 samples + 1 pad)
#define SCAN_OFF 8448                 // 256*33 floats of staging
#define SCAN_STR 281                  // per-array scan stride (280 + 1 pad)
#define H_OFF 10136                   // 16B-aligned H table (3 bands x 32)
#define LDSF  10232                   // 40928 B -> exactly 4 blocks/CU

__device__ __forceinline__ void compute_coeffs(float level_in, float b0[3], float na1[3], float na2[3]) {
    const float FD[3] = {270.0f, 800.0f, 2300.0f};
    const float FN[3] = {500.0f, 1500.0f, 2500.0f};
    const float FB[3] = {730.0f, 2100.0f, 3000.0f};
    float level = fminf(fmaxf(level_in, 0.0f), 1.0f);
    float t_low  = fminf(fmaxf(level * 2.0f, 0.0f), 1.0f);
    float t_high = fminf(fmaxf((level - 0.5f) * 2.0f, 0.0f), 1.0f);
    bool hi = (level >= 0.5f);
    const float W0 = (float)(2.0 * M_PI / 16000.0);
    #pragma unroll
    for (int k = 0; k < 3; ++k) {
        float f, q;
        if (hi) { f = (1.0f - t_high) * FN[k] + t_high * FB[k];
                  q = (1.0f - t_high) * 8.0f  + t_high * 12.0f; }
        else    { f = (1.0f - t_low) * FD[k] + t_low * FN[k];
                  q = (1.0f - t_low) * 5.0f  + t_low * 8.0f; }
        float omega = W0 * f;
        float sn = sinf(omega), cs = cosf(omega);
        float alpha = sn / (2.0f * fmaxf(q, 0.5f));
        float a0 = 1.0f + alpha;
        b0[k]  = alpha / a0;             // b2 == -b0 exactly
        na1[k] = (2.0f * cs) / a0;       // -a1
        na2[k] = -((1.0f - alpha) / a0); // -a2
    }
}

#define STEP3(XT, XTM2, SUMV)                                                    \
    {                                                                            \
        float d = (XT) - (XTM2);                                                 \
        float e0 = fmaf(b0[0], d, na2[0] * y2[0]);                               \
        float e1 = fmaf(b0[1], d, na2[1] * y2[1]);                               \
        float e2 = fmaf(b0[2], d, na2[2] * y2[2]);                               \
        float yy0 = fmaf(na1[0], y1[0], e0);                                     \
        float yy1 = fmaf(na1[1], y1[1], e1);                                     \
        float yy2 = fmaf(na1[2], y1[2], e2);                                     \
        y2[0] = y1[0]; y1[0] = yy0;                                              \
        y2[1] = y1[1]; y1[1] = yy1;                                              \
        y2[2] = y1[2]; y1[2] = yy2;                                              \
        SUMV = (yy0 + yy1 + yy2);                                                \
    }

// 2x2 matrix multiply: R = X * Y
#define MMUL(R00,R01,R10,R11, X00,X01,X10,X11, Y00,Y01,Y10,Y11)                  \
    {                                                                            \
        R00 = X00*Y00 + X01*Y10; R01 = X00*Y01 + X01*Y11;                        \
        R10 = X10*Y00 + X11*Y10; R11 = X10*Y01 + X11*Y11;                        \
    }

__global__ __launch_bounds__(TPB, 4)
void formant_onepass(const float* __restrict__ x, const float* __restrict__ lvl,
                     float* __restrict__ out)
{
    __shared__ float lds[LDSF];

    const int tid = threadIdx.x;
    const int row = blockIdx.x >> 4;
    const int seg = blockIdx.x & (SEGS - 1);

    float b0[3], na1[3], na2[3];
    compute_coeffs(lvl[row], b0, na1, na2);

    const float* xrow = x + (size_t)row * S_LEN;
    const size_t segBase = (size_t)seg * SEG_SAMPS;
    const float* xc = xrow + segBase + (size_t)tid * CCH;

    // -------- phase 1a: main-chunk zero-state; band-sum -> LDS staging --------
    {
        float xm1 = 0.f, xm2 = 0.f;
        if (seg > 0 || tid > 0) { float2 t2 = *(const float2*)(xc - 2); xm2 = t2.x; xm1 = t2.y; }
        float y1[3] = {0.f,0.f,0.f}, y2[3] = {0.f,0.f,0.f};
        const float4* xv = (const float4*)xc;
        float* myob = lds + tid * OBSTR;
        float4 buf[4];
        #pragma unroll
        for (int j = 0; j < 4; ++j) buf[j] = xv[j];
        #pragma unroll
        for (int i = 0; i < 8; ++i) {
            float4 q = buf[i & 3];
            if (i + 4 < 8) buf[i & 3] = xv[i + 4];
            float4 o;
            STEP3(q.x, xm2, o.x)
            STEP3(q.y, xm1, o.y)
            STEP3(q.z, q.x, o.z)
            STEP3(q.w, q.y, o.w)
            xm2 = q.z; xm1 = q.w;
            // scalar LDS writes: bank=(33*tid + 4i+c)%32 -> exactly 2-way (free)
            myob[4*i + 0] = o.x;
            myob[4*i + 1] = o.y;
            myob[4*i + 2] = o.z;
            myob[4*i + 3] = o.w;
        }
        // end-of-chunk states -> scan arrays at index WCH+tid (consecutive, conflict-free)
        lds[SCAN_OFF + 0*SCAN_STR + WCH + tid] = y1[0];
        lds[SCAN_OFF + 1*SCAN_STR + WCH + tid] = y2[0];
        lds[SCAN_OFF + 2*SCAN_STR + WCH + tid] = y1[1];
        lds[SCAN_OFF + 3*SCAN_STR + WCH + tid] = y2[1];
        lds[SCAN_OFF + 4*SCAN_STR + WCH + tid] = y1[2];
        lds[SCAN_OFF + 5*SCAN_STR + WCH + tid] = y2[2];
    }

    // -------- phase 1b: warmup chunks (threads 0..23) --------
    if (tid < WCH) {
        if (seg == 0) {
            #pragma unroll
            for (int e = 0; e < 6; ++e) lds[SCAN_OFF + e*SCAN_STR + tid] = 0.f;  // exact
        } else {
            const float* xw = xrow + segBase - (size_t)(WCH * CCH) + (size_t)tid * CCH;
            float2 t2 = *(const float2*)(xw - 2);
            float y1[3] = {0.f,0.f,0.f}, y2[3] = {0.f,0.f,0.f};
            float p2 = t2.x, p1 = t2.y, dummy;
            const float4* xv = (const float4*)xw;
            float4 buf[4];
            #pragma unroll
            for (int j = 0; j < 4; ++j) buf[j] = xv[j];
            #pragma unroll
            for (int i = 0; i < 8; ++i) {
                float4 q = buf[i & 3];
                if (i + 4 < 8) buf[i & 3] = xv[i + 4];
                STEP3(q.x, p2, dummy)
                STEP3(q.y, p1, dummy)
                STEP3(q.z, q.x, dummy)
                STEP3(q.w, q.y, dummy)
                p2 = q.z; p1 = q.w;
            }
            (void)dummy;
            lds[SCAN_OFF + 0*SCAN_STR + tid] = y1[0];
            lds[SCAN_OFF + 1*SCAN_STR + tid] = y2[0];
            lds[SCAN_OFF + 2*SCAN_STR + tid] = y1[1];
            lds[SCAN_OFF + 3*SCAN_STR + tid] = y2[1];
            lds[SCAN_OFF + 4*SCAN_STR + tid] = y1[2];
            lds[SCAN_OFF + 5*SCAN_STR + tid] = y2[2];
        }
    }
    __syncthreads();

    // -------- phase 2: block-local affine scan over 280 chunk states + H table --------
    // lanes 0..23 fold 5 chunks, lanes 24..63 fold 4 (24*5 + 40*4 = 280)
    {
        const int wv = tid >> 6, ln = tid & 63;
        if (wv < 3) {
            const float A1 = na1[wv], A2 = na2[wv];
            float hm1 = 1.f, hm2 = 0.f, hm3 = 0.f;   // H(-1)=1, H(-2)=0
            for (int i = 0; i < CCH; ++i) {
                float h = fmaf(A1, hm1, A2 * hm2);
                hm3 = hm2; hm2 = hm1; hm1 = h;
                if (ln == 0) lds[H_OFF + wv * CCH + i] = h;   // H(i)
            }
            const float H00 = hm1, H01 = A2 * hm2;
            const float H10 = hm2, H11 = A2 * hm3;

            float* z1p = lds + SCAN_OFF + (2*wv) * SCAN_STR;
            float* z2p = lds + SCAN_OFF + (2*wv + 1) * SCAN_STR;

            const int cnt = (ln < 24) ? 5 : 4;
            const int beg = (ln < 24) ? 5 * ln : 120 + 4 * (ln - 24);

            float s1 = 0.f, s2 = 0.f;
            for (int j = 0; j < cnt; ++j) {
                float z1 = z1p[beg + j], z2 = z2p[beg + j];
                float n1 = z1 + H00 * s1 + H01 * s2;
                float n2 = z2 + H10 * s1 + H11 * s2;
                s1 = n1; s2 = n2;
            }
            float B00,B01,B10,B11, C00,C01,C10,C11;
            MMUL(B00,B01,B10,B11, H00,H01,H10,H11, H00,H01,H10,H11)   // H^2
            MMUL(C00,C01,C10,C11, B00,B01,B10,B11, B00,B01,B10,B11)   // H^4
            float A00 = C00, A01 = C01, A10 = C10, A11 = C11;
            if (cnt == 5) {
                float D00,D01,D10,D11;
                MMUL(D00,D01,D10,D11, C00,C01,C10,C11, H00,H01,H10,H11)
                A00 = D00; A01 = D01; A10 = D10; A11 = D11;
            }
            float bb1 = s1, bb2 = s2;
            for (int d = 1; d < 64; d <<= 1) {
                float iA00 = __shfl_up(A00, d), iA01 = __shfl_up(A01, d);
                float iA10 = __shfl_up(A10, d), iA11 = __shfl_up(A11, d);
                float ib1  = __shfl_up(bb1, d), ib2  = __shfl_up(bb2, d);
                if (ln >= d) {
                    float nb1 = A00 * ib1 + A01 * ib2 + bb1;
                    float nb2 = A10 * ib1 + A11 * ib2 + bb2;
                    float n00, n01, n10, n11;
                    MMUL(n00,n01,n10,n11, A00,A01,A10,A11, iA00,iA01,iA10,iA11)
                    A00 = n00; A01 = n01; A10 = n10; A11 = n11;
                    bb1 = nb1; bb2 = nb2;
                }
            }
            float e1 = __shfl_up(bb1, 1), e2 = __shfl_up(bb2, 1);
            if (ln == 0) { e1 = 0.f; e2 = 0.f; }

            // replay: overwrite z with corrected chunk-ENTRY states (y[-1], y[-2])
            s1 = e1; s2 = e2;
            for (int j = 0; j < cnt; ++j) {
                int w = beg + j;
                float z1 = z1p[w], z2 = z2p[w];
                z1p[w] = s1; z2p[w] = s2;
                float n1 = z1 + H00 * s1 + H01 * s2;
                float n2 = z2 + H10 * s1 + H11 * s2;
                s1 = n1; s2 = n2;
            }
        }
    }
    __syncthreads();

    // -------- phase 3: out[f] = is3*(szs + sum_k c1k*H(t) + c2k*H(t-1)) --------
    // Direct coalesced global stores in cooperative order; no x, no chain.
    {
        const float is3 = 0.57735026918962576f;   // 1/sqrt(3)
        float4* obase = (float4*)(out + (size_t)row * S_LEN + segBase);
        #pragma unroll
        for (int j = 0; j < 8; ++j) {
            const int f   = j * TPB + tid;        // output float4 index (coalesced)
            const int ch  = f >> 3;               // source chunk
            const int off = f & 7;                // float4 within chunk
            const int t   = off * 4;
            const float* sp = lds + ch * OBSTR + t;       // szs, 2 lanes/bank (free)
            float o0 = sp[0], o1 = sp[1], o2 = sp[2], o3 = sp[3];
            #pragma unroll
            for (int k = 0; k < 3; ++k) {
                const float c1 = lds[SCAN_OFF + (2*k)   * SCAN_STR + WCH + ch];
                const float c2 = na2[k] * lds[SCAN_OFF + (2*k+1) * SCAN_STR + WCH + ch];
                const float4 hv = *(const float4*)&lds[H_OFF + k * CCH + t];   // H(t..t+3)
                const float hm = (off == 0) ? 1.0f : lds[H_OFF + k * CCH + t - 1];
                o0 = fmaf(c1, hv.x, fmaf(c2, hm,   o0));
                o1 = fmaf(c1, hv.y, fmaf(c2, hv.x, o1));
                o2 = fmaf(c1, hv.z, fmaf(c2, hv.y, o2));
                o3 = fmaf(c1, hv.w, fmaf(c2, hv.z, o3));
            }
            float4 o = { o0 * is3, o1 * is3, o2 * is3, o3 * is3 };
            obase[f] = o;
        }
    }
}

extern "C" void kernel_launch(void* const* d_in, const int* in_sizes, int n_in,
                              void* d_out, int out_size, void* d_ws, size_t ws_size,
                              hipStream_t stream) {
    const float* audio = (const float*)d_in[0];
    const float* level = (const float*)d_in[1];
    float* out = (float*)d_out;
    (void)in_sizes; (void)n_in; (void)d_ws; (void)ws_size; (void)out_size;

    formant_onepass<<<BATCHES * SEGS, TPB, 0, stream>>>(audio, level, out);
}

// Round 13
// 57.535 us; speedup vs baseline: 2.6998x; 1.0239x over previous
//
#include <hip/hip_runtime.h>
#include <math.h>

#ifndef M_PI
#define M_PI 3.14159265358979323846
#endif

#define BATCHES 256
#define S_LEN   131072

// One kernel, independent blocks, truncated-warmup linear recurrence.
// Block = 256 threads x 32-sample chunks = 8192-sample segment; warmup 24
// chunks (768 samples): worst pole r=0.98948 -> truncation ~2.8e-3 vs
// threshold 2.03e-2 (measured absmax 0.0039, r12). Phase 3 uses the
// homogeneous-correction identity: y(t) = y_zs(t) + c1*H(t) + c2*H(t-1),
// y_zs band-sum staged in LDS, H in LDS -- no x re-read, no serial chain,
// direct coalesced global stores, 2 barriers.
//
// r13 delta vs r12 (single variable): NON-TEMPORAL output stores.
// r12 counters showed FETCH=74MB < |x|=134MB -- x is partially L3-resident
// across replays, evicted only by the 134MB write stream (134+134 > 256MB L3).
// nt stores mark output no-allocate -> x should become fully L3-resident,
// steady-state HBM traffic ~= writes only.
//
// Operating point (r7-r11 evidence): 4 blocks/CU, launch_bounds(256,4),
// no cross-phase register arrays (compiler clamps VGPR and spills: r8=32,
// r9=40, r10=64+spill). VGPR here: 52, no scratch.
#define TPB   256
#define CCH   32
#define SEGS  16                      // segments per row
#define SEG_SAMPS (TPB * CCH)         // 8192
#define WCH   24                      // warmup chunks
#define NCH   (TPB + WCH)             // 280 chunks scanned
#define OBSTR 33                      // staging stride (32 samples + 1 pad)
#define SCAN_OFF 8448                 // 256*33 floats of staging
#define SCAN_STR 281                  // per-array scan stride (280 + 1 pad)
#define H_OFF 10136                   // 16B-aligned H table (3 bands x 32)
#define LDSF  10232                   // 40928 B -> exactly 4 blocks/CU

typedef float v4f __attribute__((ext_vector_type(4)));

__device__ __forceinline__ void compute_coeffs(float level_in, float b0[3], float na1[3], float na2[3]) {
    const float FD[3] = {270.0f, 800.0f, 2300.0f};
    const float FN[3] = {500.0f, 1500.0f, 2500.0f};
    const float FB[3] = {730.0f, 2100.0f, 3000.0f};
    float level = fminf(fmaxf(level_in, 0.0f), 1.0f);
    float t_low  = fminf(fmaxf(level * 2.0f, 0.0f), 1.0f);
    float t_high = fminf(fmaxf((level - 0.5f) * 2.0f, 0.0f), 1.0f);
    bool hi = (level >= 0.5f);
    const float W0 = (float)(2.0 * M_PI / 16000.0);
    #pragma unroll
    for (int k = 0; k < 3; ++k) {
        float f, q;
        if (hi) { f = (1.0f - t_high) * FN[k] + t_high * FB[k];
                  q = (1.0f - t_high) * 8.0f  + t_high * 12.0f; }
        else    { f = (1.0f - t_low) * FD[k] + t_low * FN[k];
                  q = (1.0f - t_low) * 5.0f  + t_low * 8.0f; }
        float omega = W0 * f;
        float sn = sinf(omega), cs = cosf(omega);
        float alpha = sn / (2.0f * fmaxf(q, 0.5f));
        float a0 = 1.0f + alpha;
        b0[k]  = alpha / a0;             // b2 == -b0 exactly
        na1[k] = (2.0f * cs) / a0;       // -a1
        na2[k] = -((1.0f - alpha) / a0); // -a2
    }
}

#define STEP3(XT, XTM2, SUMV)                                                    \
    {                                                                            \
        float d = (XT) - (XTM2);                                                 \
        float e0 = fmaf(b0[0], d, na2[0] * y2[0]);                               \
        float e1 = fmaf(b0[1], d, na2[1] * y2[1]);                               \
        float e2 = fmaf(b0[2], d, na2[2] * y2[2]);                               \
        float yy0 = fmaf(na1[0], y1[0], e0);                                     \
        float yy1 = fmaf(na1[1], y1[1], e1);                                     \
        float yy2 = fmaf(na1[2], y1[2], e2);                                     \
        y2[0] = y1[0]; y1[0] = yy0;                                              \
        y2[1] = y1[1]; y1[1] = yy1;                                              \
        y2[2] = y1[2]; y1[2] = yy2;                                              \
        SUMV = (yy0 + yy1 + yy2);                                                \
    }

// 2x2 matrix multiply: R = X * Y
#define MMUL(R00,R01,R10,R11, X00,X01,X10,X11, Y00,Y01,Y10,Y11)                  \
    {                                                                            \
        R00 = X00*Y00 + X01*Y10; R01 = X00*Y01 + X01*Y11;                        \
        R10 = X10*Y00 + X11*Y10; R11 = X10*Y01 + X11*Y11;                        \
    }

__global__ __launch_bounds__(TPB, 4)
void formant_onepass(const float* __restrict__ x, const float* __restrict__ lvl,
                     float* __restrict__ out)
{
    __shared__ float lds[LDSF];

    const int tid = threadIdx.x;
    const int row = blockIdx.x >> 4;
    const int seg = blockIdx.x & (SEGS - 1);

    float b0[3], na1[3], na2[3];
    compute_coeffs(lvl[row], b0, na1, na2);

    const float* xrow = x + (size_t)row * S_LEN;
    const size_t segBase = (size_t)seg * SEG_SAMPS;
    const float* xc = xrow + segBase + (size_t)tid * CCH;

    // -------- phase 1a: main-chunk zero-state; band-sum -> LDS staging --------
    {
        float xm1 = 0.f, xm2 = 0.f;
        if (seg > 0 || tid > 0) { float2 t2 = *(const float2*)(xc - 2); xm2 = t2.x; xm1 = t2.y; }
        float y1[3] = {0.f,0.f,0.f}, y2[3] = {0.f,0.f,0.f};
        const float4* xv = (const float4*)xc;
        float* myob = lds + tid * OBSTR;
        float4 buf[4];
        #pragma unroll
        for (int j = 0; j < 4; ++j) buf[j] = xv[j];
        #pragma unroll
        for (int i = 0; i < 8; ++i) {
            float4 q = buf[i & 3];
            if (i + 4 < 8) buf[i & 3] = xv[i + 4];
            float4 o;
            STEP3(q.x, xm2, o.x)
            STEP3(q.y, xm1, o.y)
            STEP3(q.z, q.x, o.z)
            STEP3(q.w, q.y, o.w)
            xm2 = q.z; xm1 = q.w;
            // scalar LDS writes: bank=(33*tid + 4i+c)%32 -> exactly 2-way (free)
            myob[4*i + 0] = o.x;
            myob[4*i + 1] = o.y;
            myob[4*i + 2] = o.z;
            myob[4*i + 3] = o.w;
        }
        // end-of-chunk states -> scan arrays at index WCH+tid (consecutive, conflict-free)
        lds[SCAN_OFF + 0*SCAN_STR + WCH + tid] = y1[0];
        lds[SCAN_OFF + 1*SCAN_STR + WCH + tid] = y2[0];
        lds[SCAN_OFF + 2*SCAN_STR + WCH + tid] = y1[1];
        lds[SCAN_OFF + 3*SCAN_STR + WCH + tid] = y2[1];
        lds[SCAN_OFF + 4*SCAN_STR + WCH + tid] = y1[2];
        lds[SCAN_OFF + 5*SCAN_STR + WCH + tid] = y2[2];
    }

    // -------- phase 1b: warmup chunks (threads 0..23) --------
    if (tid < WCH) {
        if (seg == 0) {
            #pragma unroll
            for (int e = 0; e < 6; ++e) lds[SCAN_OFF + e*SCAN_STR + tid] = 0.f;  // exact
        } else {
            const float* xw = xrow + segBase - (size_t)(WCH * CCH) + (size_t)tid * CCH;
            float2 t2 = *(const float2*)(xw - 2);
            float y1[3] = {0.f,0.f,0.f}, y2[3] = {0.f,0.f,0.f};
            float p2 = t2.x, p1 = t2.y, dummy;
            const float4* xv = (const float4*)xw;
            float4 buf[4];
            #pragma unroll
            for (int j = 0; j < 4; ++j) buf[j] = xv[j];
            #pragma unroll
            for (int i = 0; i < 8; ++i) {
                float4 q = buf[i & 3];
                if (i + 4 < 8) buf[i & 3] = xv[i + 4];
                STEP3(q.x, p2, dummy)
                STEP3(q.y, p1, dummy)
                STEP3(q.z, q.x, dummy)
                STEP3(q.w, q.y, dummy)
                p2 = q.z; p1 = q.w;
            }
            (void)dummy;
            lds[SCAN_OFF + 0*SCAN_STR + tid] = y1[0];
            lds[SCAN_OFF + 1*SCAN_STR + tid] = y2[0];
            lds[SCAN_OFF + 2*SCAN_STR + tid] = y1[1];
            lds[SCAN_OFF + 3*SCAN_STR + tid] = y2[1];
            lds[SCAN_OFF + 4*SCAN_STR + tid] = y1[2];
            lds[SCAN_OFF + 5*SCAN_STR + tid] = y2[2];
        }
    }
    __syncthreads();

    // -------- phase 2: block-local affine scan over 280 chunk states + H table --------
    // lanes 0..23 fold 5 chunks, lanes 24..63 fold 4 (24*5 + 40*4 = 280)
    {
        const int wv = tid >> 6, ln = tid & 63;
        if (wv < 3) {
            const float A1 = na1[wv], A2 = na2[wv];
            float hm1 = 1.f, hm2 = 0.f, hm3 = 0.f;   // H(-1)=1, H(-2)=0
            for (int i = 0; i < CCH; ++i) {
                float h = fmaf(A1, hm1, A2 * hm2);
                hm3 = hm2; hm2 = hm1; hm1 = h;
                if (ln == 0) lds[H_OFF + wv * CCH + i] = h;   // H(i)
            }
            const float H00 = hm1, H01 = A2 * hm2;
            const float H10 = hm2, H11 = A2 * hm3;

            float* z1p = lds + SCAN_OFF + (2*wv) * SCAN_STR;
            float* z2p = lds + SCAN_OFF + (2*wv + 1) * SCAN_STR;

            const int cnt = (ln < 24) ? 5 : 4;
            const int beg = (ln < 24) ? 5 * ln : 120 + 4 * (ln - 24);

            float s1 = 0.f, s2 = 0.f;
            for (int j = 0; j < cnt; ++j) {
                float z1 = z1p[beg + j], z2 = z2p[beg + j];
                float n1 = z1 + H00 * s1 + H01 * s2;
                float n2 = z2 + H10 * s1 + H11 * s2;
                s1 = n1; s2 = n2;
            }
            float B00,B01,B10,B11, C00,C01,C10,C11;
            MMUL(B00,B01,B10,B11, H00,H01,H10,H11, H00,H01,H10,H11)   // H^2
            MMUL(C00,C01,C10,C11, B00,B01,B10,B11, B00,B01,B10,B11)   // H^4
            float A00 = C00, A01 = C01, A10 = C10, A11 = C11;
            if (cnt == 5) {
                float D00,D01,D10,D11;
                MMUL(D00,D01,D10,D11, C00,C01,C10,C11, H00,H01,H10,H11)
                A00 = D00; A01 = D01; A10 = D10; A11 = D11;
            }
            float bb1 = s1, bb2 = s2;
            for (int d = 1; d < 64; d <<= 1) {
                float iA00 = __shfl_up(A00, d), iA01 = __shfl_up(A01, d);
                float iA10 = __shfl_up(A10, d), iA11 = __shfl_up(A11, d);
                float ib1  = __shfl_up(bb1, d), ib2  = __shfl_up(bb2, d);
                if (ln >= d) {
                    float nb1 = A00 * ib1 + A01 * ib2 + bb1;
                    float nb2 = A10 * ib1 + A11 * ib2 + bb2;
                    float n00, n01, n10, n11;
                    MMUL(n00,n01,n10,n11, A00,A01,A10,A11, iA00,iA01,iA10,iA11)
                    A00 = n00; A01 = n01; A10 = n10; A11 = n11;
                    bb1 = nb1; bb2 = nb2;
                }
            }
            float e1 = __shfl_up(bb1, 1), e2 = __shfl_up(bb2, 1);
            if (ln == 0) { e1 = 0.f; e2 = 0.f; }

            // replay: overwrite z with corrected chunk-ENTRY states (y[-1], y[-2])
            s1 = e1; s2 = e2;
            for (int j = 0; j < cnt; ++j) {
                int w = beg + j;
                float z1 = z1p[w], z2 = z2p[w];
                z1p[w] = s1; z2p[w] = s2;
                float n1 = z1 + H00 * s1 + H01 * s2;
                float n2 = z2 + H10 * s1 + H11 * s2;
                s1 = n1; s2 = n2;
            }
        }
    }
    __syncthreads();

    // -------- phase 3: out[f] = is3*(szs + sum_k c1k*H(t) + c2k*H(t-1)) --------
    // Direct coalesced NON-TEMPORAL stores (no L2/L3 allocate -> x stays L3-resident).
    {
        const float is3 = 0.57735026918962576f;   // 1/sqrt(3)
        float* obase = out + (size_t)row * S_LEN + segBase;
        #pragma unroll
        for (int j = 0; j < 8; ++j) {
            const int f   = j * TPB + tid;        // output float4 index (coalesced)
            const int ch  = f >> 3;               // source chunk
            const int off = f & 7;                // float4 within chunk
            const int t   = off * 4;
            const float* sp = lds + ch * OBSTR + t;       // szs, 2 lanes/bank (free)
            float o0 = sp[0], o1 = sp[1], o2 = sp[2], o3 = sp[3];
            #pragma unroll
            for (int k = 0; k < 3; ++k) {
                const float c1 = lds[SCAN_OFF + (2*k)   * SCAN_STR + WCH + ch];
                const float c2 = na2[k] * lds[SCAN_OFF + (2*k+1) * SCAN_STR + WCH + ch];
                const float4 hv = *(const float4*)&lds[H_OFF + k * CCH + t];   // H(t..t+3)
                const float hm = (off == 0) ? 1.0f : lds[H_OFF + k * CCH + t - 1];
                o0 = fmaf(c1, hv.x, fmaf(c2, hm,   o0));
                o1 = fmaf(c1, hv.y, fmaf(c2, hv.x, o1));
                o2 = fmaf(c1, hv.z, fmaf(c2, hv.y, o2));
                o3 = fmaf(c1, hv.w, fmaf(c2, hv.z, o3));
            }
            v4f o = { o0 * is3, o1 * is3, o2 * is3, o3 * is3 };
            __builtin_nontemporal_store(o, (v4f*)(obase + (size_t)f * 4));
        }
    }
}

extern "C" void kernel_launch(void* const* d_in, const int* in_sizes, int n_in,
                              void* d_out, int out_size, void* d_ws, size_t ws_size,
                              hipStream_t stream) {
    const float* audio = (const float*)d_in[0];
    const float* level = (const float*)d_in[1];
    float* out = (float*)d_out;
    (void)in_sizes; (void)n_in; (void)d_ws; (void)ws_size; (void)out_size;

    formant_onepass<<<BATCHES * SEGS, TPB, 0, stream>>>(audio, level, out);
}

// Round 14
// 57.205 us; speedup vs baseline: 2.7154x; 1.0058x over previous
//
#include <hip/hip_runtime.h>
#include <math.h>

#ifndef M_PI
#define M_PI 3.14159265358979323846
#endif

#define BATCHES 256
#define S_LEN   131072

// One kernel, independent blocks, truncated-warmup linear recurrence.
// Block = 320 threads (5 waves): threads 0..255 own 32-sample main chunks
// (8192-sample segment), threads 256..279 (wave 4) compute the 24 warmup
// chunks CONCURRENTLY (r13 had warmup inside wave 0 -> phase-1 took 2x).
// Warmup 768 samples: worst pole r=0.98948 -> truncation ~2.8e-3 vs
// threshold 2.03e-2 (measured absmax 0.0039, r12/r13).
// Phase 3: homogeneous-correction identity y(t)=y_zs(t)+c1*H(t)+c2*H(t-1),
// y_zs band-sum + H staged in LDS; no x re-read, no serial chain, direct
// coalesced non-temporal stores; 2 barriers.
// Coeffs via __sinf/__cosf (native v_sin/v_cos; ~1e-3 output error, r14).
//
// Operating point (r7-r13 evidence): 4 blocks/CU pinned by 40928B LDS,
// VGPR ~52 no spill; avoid min-waves bounds that trigger the VGPR clamp
// (r8=32, r9=40, r10=64+spill). nt stores kept (r13: small win).
#define TPB   320
#define MAINT 256
#define CCH   32
#define SEGS  16                      // segments per row
#define SEG_SAMPS (MAINT * CCH)       // 8192
#define WCH   24                      // warmup chunks
#define OBSTR 33                      // staging stride (32 samples + 1 pad)
#define SCAN_OFF 8448                 // 256*33 floats of staging
#define SCAN_STR 281                  // per-array scan stride (280 + 1 pad)
#define H_OFF 10136                   // 16B-aligned H table (3 bands x 32)
#define LDSF  10232                   // 40928 B -> exactly 4 blocks/CU

typedef float v4f __attribute__((ext_vector_type(4)));

__device__ __forceinline__ void compute_coeffs(float level_in, float b0[3], float na1[3], float na2[3]) {
    const float FD[3] = {270.0f, 800.0f, 2300.0f};
    const float FN[3] = {500.0f, 1500.0f, 2500.0f};
    const float FB[3] = {730.0f, 2100.0f, 3000.0f};
    float level = fminf(fmaxf(level_in, 0.0f), 1.0f);
    float t_low  = fminf(fmaxf(level * 2.0f, 0.0f), 1.0f);
    float t_high = fminf(fmaxf((level - 0.5f) * 2.0f, 0.0f), 1.0f);
    bool hi = (level >= 0.5f);
    const float W0 = (float)(2.0 * M_PI / 16000.0);
    #pragma unroll
    for (int k = 0; k < 3; ++k) {
        float f, q;
        if (hi) { f = (1.0f - t_high) * FN[k] + t_high * FB[k];
                  q = (1.0f - t_high) * 8.0f  + t_high * 12.0f; }
        else    { f = (1.0f - t_low) * FD[k] + t_low * FN[k];
                  q = (1.0f - t_low) * 5.0f  + t_low * 8.0f; }
        float omega = W0 * f;
        float sn = __sinf(omega), cs = __cosf(omega);   // native v_sin/v_cos
        float alpha = sn / (2.0f * fmaxf(q, 0.5f));
        float a0 = 1.0f + alpha;
        b0[k]  = alpha / a0;             // b2 == -b0 exactly
        na1[k] = (2.0f * cs) / a0;       // -a1
        na2[k] = -((1.0f - alpha) / a0); // -a2
    }
}

#define STEP3(XT, XTM2, SUMV)                                                    \
    {                                                                            \
        float d = (XT) - (XTM2);                                                 \
        float e0 = fmaf(b0[0], d, na2[0] * y2[0]);                               \
        float e1 = fmaf(b0[1], d, na2[1] * y2[1]);                               \
        float e2 = fmaf(b0[2], d, na2[2] * y2[2]);                               \
        float yy0 = fmaf(na1[0], y1[0], e0);                                     \
        float yy1 = fmaf(na1[1], y1[1], e1);                                     \
        float yy2 = fmaf(na1[2], y1[2], e2);                                     \
        y2[0] = y1[0]; y1[0] = yy0;                                              \
        y2[1] = y1[1]; y1[1] = yy1;                                              \
        y2[2] = y1[2]; y1[2] = yy2;                                              \
        SUMV = (yy0 + yy1 + yy2);                                                \
    }

// 2x2 matrix multiply: R = X * Y
#define MMUL(R00,R01,R10,R11, X00,X01,X10,X11, Y00,Y01,Y10,Y11)                  \
    {                                                                            \
        R00 = X00*Y00 + X01*Y10; R01 = X00*Y01 + X01*Y11;                        \
        R10 = X10*Y00 + X11*Y10; R11 = X10*Y01 + X11*Y11;                        \
    }

__global__ __launch_bounds__(TPB, 4)
void formant_onepass(const float* __restrict__ x, const float* __restrict__ lvl,
                     float* __restrict__ out)
{
    __shared__ float lds[LDSF];

    const int tid = threadIdx.x;
    const int row = blockIdx.x >> 4;
    const int seg = blockIdx.x & (SEGS - 1);

    float b0[3], na1[3], na2[3];
    compute_coeffs(lvl[row], b0, na1, na2);

    const float* xrow = x + (size_t)row * S_LEN;
    const size_t segBase = (size_t)seg * SEG_SAMPS;

    // -------- phase 1a: main-chunk zero-state (threads 0..255) --------
    if (tid < MAINT) {
        const float* xc = xrow + segBase + (size_t)tid * CCH;
        float xm1 = 0.f, xm2 = 0.f;
        if (seg > 0 || tid > 0) { float2 t2 = *(const float2*)(xc - 2); xm2 = t2.x; xm1 = t2.y; }
        float y1[3] = {0.f,0.f,0.f}, y2[3] = {0.f,0.f,0.f};
        const float4* xv = (const float4*)xc;
        float* myob = lds + tid * OBSTR;
        float4 buf[4];
        #pragma unroll
        for (int j = 0; j < 4; ++j) buf[j] = xv[j];
        #pragma unroll
        for (int i = 0; i < 8; ++i) {
            float4 q = buf[i & 3];
            if (i + 4 < 8) buf[i & 3] = xv[i + 4];
            float4 o;
            STEP3(q.x, xm2, o.x)
            STEP3(q.y, xm1, o.y)
            STEP3(q.z, q.x, o.z)
            STEP3(q.w, q.y, o.w)
            xm2 = q.z; xm1 = q.w;
            // scalar LDS writes: bank=(33*tid + 4i+c)%32 -> exactly 2-way (free)
            myob[4*i + 0] = o.x;
            myob[4*i + 1] = o.y;
            myob[4*i + 2] = o.z;
            myob[4*i + 3] = o.w;
        }
        // end-of-chunk states -> scan arrays at index WCH+tid
        lds[SCAN_OFF + 0*SCAN_STR + WCH + tid] = y1[0];
        lds[SCAN_OFF + 1*SCAN_STR + WCH + tid] = y2[0];
        lds[SCAN_OFF + 2*SCAN_STR + WCH + tid] = y1[1];
        lds[SCAN_OFF + 3*SCAN_STR + WCH + tid] = y2[1];
        lds[SCAN_OFF + 4*SCAN_STR + WCH + tid] = y1[2];
        lds[SCAN_OFF + 5*SCAN_STR + WCH + tid] = y2[2];
    }
    // -------- phase 1b: warmup chunks on DEDICATED wave 4 (threads 256..279) --------
    else if (tid < MAINT + WCH) {
        const int wid = tid - MAINT;
        if (seg == 0) {
            #pragma unroll
            for (int e = 0; e < 6; ++e) lds[SCAN_OFF + e*SCAN_STR + wid] = 0.f;  // exact
        } else {
            const float* xw = xrow + segBase - (size_t)(WCH * CCH) + (size_t)wid * CCH;
            float2 t2 = *(const float2*)(xw - 2);
            float y1[3] = {0.f,0.f,0.f}, y2[3] = {0.f,0.f,0.f};
            float p2 = t2.x, p1 = t2.y, dummy;
            const float4* xv = (const float4*)xw;
            float4 buf[4];
            #pragma unroll
            for (int j = 0; j < 4; ++j) buf[j] = xv[j];
            #pragma unroll
            for (int i = 0; i < 8; ++i) {
                float4 q = buf[i & 3];
                if (i + 4 < 8) buf[i & 3] = xv[i + 4];
                STEP3(q.x, p2, dummy)
                STEP3(q.y, p1, dummy)
                STEP3(q.z, q.x, dummy)
                STEP3(q.w, q.y, dummy)
                p2 = q.z; p1 = q.w;
            }
            (void)dummy;
            lds[SCAN_OFF + 0*SCAN_STR + wid] = y1[0];
            lds[SCAN_OFF + 1*SCAN_STR + wid] = y2[0];
            lds[SCAN_OFF + 2*SCAN_STR + wid] = y1[1];
            lds[SCAN_OFF + 3*SCAN_STR + wid] = y2[1];
            lds[SCAN_OFF + 4*SCAN_STR + wid] = y1[2];
            lds[SCAN_OFF + 5*SCAN_STR + wid] = y2[2];
        }
    }
    __syncthreads();

    // -------- phase 2: block-local affine scan over 280 chunk states + H table --------
    // waves 0..2; lanes 0..23 fold 5 chunks, lanes 24..63 fold 4 (24*5+40*4=280)
    {
        const int wv = tid >> 6, ln = tid & 63;
        if (wv < 3) {
            const float A1 = na1[wv], A2 = na2[wv];
            float hm1 = 1.f, hm2 = 0.f, hm3 = 0.f;   // H(-1)=1, H(-2)=0
            for (int i = 0; i < CCH; ++i) {
                float h = fmaf(A1, hm1, A2 * hm2);
                hm3 = hm2; hm2 = hm1; hm1 = h;
                if (ln == 0) lds[H_OFF + wv * CCH + i] = h;   // H(i)
            }
            const float H00 = hm1, H01 = A2 * hm2;
            const float H10 = hm2, H11 = A2 * hm3;

            float* z1p = lds + SCAN_OFF + (2*wv) * SCAN_STR;
            float* z2p = lds + SCAN_OFF + (2*wv + 1) * SCAN_STR;

            const int cnt = (ln < 24) ? 5 : 4;
            const int beg = (ln < 24) ? 5 * ln : 120 + 4 * (ln - 24);

            float s1 = 0.f, s2 = 0.f;
            for (int j = 0; j < cnt; ++j) {
                float z1 = z1p[beg + j], z2 = z2p[beg + j];
                float n1 = z1 + H00 * s1 + H01 * s2;
                float n2 = z2 + H10 * s1 + H11 * s2;
                s1 = n1; s2 = n2;
            }
            float B00,B01,B10,B11, C00,C01,C10,C11;
            MMUL(B00,B01,B10,B11, H00,H01,H10,H11, H00,H01,H10,H11)   // H^2
            MMUL(C00,C01,C10,C11, B00,B01,B10,B11, B00,B01,B10,B11)   // H^4
            float A00 = C00, A01 = C01, A10 = C10, A11 = C11;
            if (cnt == 5) {
                float D00,D01,D10,D11;
                MMUL(D00,D01,D10,D11, C00,C01,C10,C11, H00,H01,H10,H11)
                A00 = D00; A01 = D01; A10 = D10; A11 = D11;
            }
            float bb1 = s1, bb2 = s2;
            for (int d = 1; d < 64; d <<= 1) {
                float iA00 = __shfl_up(A00, d), iA01 = __shfl_up(A01, d);
                float iA10 = __shfl_up(A10, d), iA11 = __shfl_up(A11, d);
                float ib1  = __shfl_up(bb1, d), ib2  = __shfl_up(bb2, d);
                if (ln >= d) {
                    float nb1 = A00 * ib1 + A01 * ib2 + bb1;
                    float nb2 = A10 * ib1 + A11 * ib2 + bb2;
                    float n00, n01, n10, n11;
                    MMUL(n00,n01,n10,n11, A00,A01,A10,A11, iA00,iA01,iA10,iA11)
                    A00 = n00; A01 = n01; A10 = n10; A11 = n11;
                    bb1 = nb1; bb2 = nb2;
                }
            }
            float e1 = __shfl_up(bb1, 1), e2 = __shfl_up(bb2, 1);
            if (ln == 0) { e1 = 0.f; e2 = 0.f; }

            // replay: overwrite z with corrected chunk-ENTRY states (y[-1], y[-2])
            s1 = e1; s2 = e2;
            for (int j = 0; j < cnt; ++j) {
                int w = beg + j;
                float z1 = z1p[w], z2 = z2p[w];
                z1p[w] = s1; z2p[w] = s2;
                float n1 = z1 + H00 * s1 + H01 * s2;
                float n2 = z2 + H10 * s1 + H11 * s2;
                s1 = n1; s2 = n2;
            }
        }
    }
    __syncthreads();

    // -------- phase 3: out[f] = is3*(szs + sum_k c1k*H(t) + c2k*H(t-1)) --------
    // Direct coalesced non-temporal stores; 2048 float4 over 320 threads.
    {
        const float is3 = 0.57735026918962576f;   // 1/sqrt(3)
        float* obase = out + (size_t)row * S_LEN + segBase;

#define EMIT_OUT(F)                                                              \
        {                                                                        \
            const int f   = (F);                                                 \
            const int ch  = f >> 3;                                              \
            const int off = f & 7;                                               \
            const int t   = off * 4;                                             \
            const float* sp = lds + ch * OBSTR + t;                              \
            float o0 = sp[0], o1 = sp[1], o2 = sp[2], o3 = sp[3];                \
            _Pragma("unroll")                                                    \
            for (int k = 0; k < 3; ++k) {                                        \
                const float c1 = lds[SCAN_OFF + (2*k)   * SCAN_STR + WCH + ch];  \
                const float c2 = na2[k] *                                        \
                    lds[SCAN_OFF + (2*k+1) * SCAN_STR + WCH + ch];               \
                const float4 hv = *(const float4*)&lds[H_OFF + k * CCH + t];     \
                const float hm = (off == 0) ? 1.0f : lds[H_OFF + k*CCH + t - 1]; \
                o0 = fmaf(c1, hv.x, fmaf(c2, hm,   o0));                         \
                o1 = fmaf(c1, hv.y, fmaf(c2, hv.x, o1));                         \
                o2 = fmaf(c1, hv.z, fmaf(c2, hv.y, o2));                         \
                o3 = fmaf(c1, hv.w, fmaf(c2, hv.z, o3));                         \
            }                                                                    \
            v4f o = { o0 * is3, o1 * is3, o2 * is3, o3 * is3 };                  \
            __builtin_nontemporal_store(o, (v4f*)(obase + (size_t)f * 4));       \
        }

        #pragma unroll
        for (int j = 0; j < 6; ++j)
            EMIT_OUT(j * TPB + tid)
        if (tid < 2048 - 6 * TPB)              // tail: 128 float4s
            EMIT_OUT(6 * TPB + tid)
#undef EMIT_OUT
    }
}

extern "C" void kernel_launch(void* const* d_in, const int* in_sizes, int n_in,
                              void* d_out, int out_size, void* d_ws, size_t ws_size,
                              hipStream_t stream) {
    const float* audio = (const float*)d_in[0];
    const float* level = (const float*)d_in[1];
    float* out = (float*)d_out;
    (void)in_sizes; (void)n_in; (void)d_ws; (void)ws_size; (void)out_size;

    formant_onepass<<<BATCHES * SEGS, TPB, 0, stream>>>(audio, level, out);
}